// Round 4
// baseline (933.640 us; speedup 1.0000x reference)
//
#include <hip/hip_runtime.h>
#include <math.h>

// (P, C, NX, NY, NT) = (2, 1, 128, 128, 8), T = 128
#define NP     2
#define NXD    128
#define NYD    128
#define NTD    8
#define PLANE  (NYD * NTD)        // 1024 sites per x-plane
#define NSITES (NP * NXD * PLANE) // 262144
#define NBLK   (NP * NXD)         // 256 blocks, one x-plane each
#define TSTEPS 128
#define DEPTH  4                  // ping-pong depth for cross-block buffer

#define AGENT __HIP_MEMORY_SCOPE_AGENT

__global__ __launch_bounds__(1024, 4) void pdhg_persist(
    const float* __restrict__ x,
    const float* __restrict__ lam,
    const float* __restrict__ tau_p,
    const float* __restrict__ sigma_p,
    const float* __restrict__ theta_p,
    unsigned long long* __restrict__ pk_g,  // DEPTH * NSITES packed {xbar,q0}
    unsigned* __restrict__ flags,           // NBLK flags, 32 uints (128B) apart
    float* __restrict__ out)
{
    __shared__ float xb_lds[2][PLANE];
    __shared__ float q1_lds[2][PLANE];
    __shared__ float q2_lds[2][PLANE];

    const int b   = blockIdx.x;        // plane = p*128 + ix
    const int tid = threadIdx.x;       // y*8 + t
    const int pp  = b >> 7;
    const int ix  = b & 127;
    const int idx = b * PLANE + tid;

    const int b_xp = (pp << 7) + ((ix + 1) & 127);
    const int b_xm = (pp << 7) + ((ix + 127) & 127);
    const int g_xp = b_xp * PLANE + tid;
    const int g_xm = b_xm * PLANE + tid;

    const int t = tid & 7;
    const int l_yp = (tid + 8) & (PLANE - 1);
    const int l_ym = (tid - 8) & (PLANE - 1);
    const int l_tp = (t == 7) ? tid - 7 : tid + 1;
    const int l_tm = (t == 0) ? tid + 7 : tid - 1;

    unsigned* flag_self = flags + b * 32;
    unsigned* flag_xp   = flags + b_xp * 32;
    unsigned* flag_xm   = flags + b_xm * 32;

    const float L = 3.605551275463989f;  // sqrt(13)
    const float s_sig = (1.f / (1.f + __expf(-sigma_p[0]))) / L;
    const float s_tau = (1.f / (1.f + __expf(-tau_p[0]))) / L;
    const float s_th  =  1.f / (1.f + __expf(-theta_p[0]));
    const float inv1s = 1.f / (1.f + s_sig);

    const float xn   = x[idx];
    const float lamc = lam[idx];
    const float lxm  = lam[g_xm];
    const float lym  = lam[b * PLANE + l_ym];
    const float ltm  = lam[b * PLANE + l_tm];

    // register-resident state for all 128 steps
    float x0v = xn, pv = xn, q0v = 0.f, q1v = 0.f, q2v = 0.f, xbv = xn;

    auto step_math = [&](float xbxp, float xbxm, float xbyp, float xbym,
                         float xbtp, float xbtm, float q0xm, float q1ym, float q2tm) {
        const float p_new = (pv + s_sig * (xbv - xn)) * inv1s;
        const float q0n = fmaxf(-lamc, fminf(lamc, q0v + s_sig * (xbxp - xbv)));
        const float q1n = fmaxf(-lamc, fminf(lamc, q1v + s_sig * (xbyp - xbv)));
        const float q2n = fmaxf(-lamc, fminf(lamc, q2v + s_sig * (xbtp - xbv)));
        // backward neighbors' new q (redundant compute -> single phase per step)
        const float q0nm = fmaxf(-lxm, fminf(lxm, q0xm + s_sig * (xbv - xbxm)));
        const float q1nm = fmaxf(-lym, fminf(lym, q1ym + s_sig * (xbv - xbym)));
        const float q2nm = fmaxf(-ltm, fminf(ltm, q2tm + s_sig * (xbv - xbtm)));
        const float div = (q0nm - q0n) + (q1nm - q1n) + (q2nm - q2n);
        const float x1 = x0v - s_tau * (p_new + div);
        const float xb_new = x1 + s_th * (x1 - x0v);
        pv = p_new; q0v = q0n; q1v = q1n; q2v = q2n;
        x0v = x1; xbv = xb_new;
    };

    auto publish = [&](int s) {
        union { float f[2]; unsigned long long u; } pk;
        pk.f[0] = xbv; pk.f[1] = q0v;
        __hip_atomic_store(&pk_g[(size_t)(s & (DEPTH - 1)) * NSITES + idx],
                           pk.u, __ATOMIC_RELAXED, AGENT);
        xb_lds[s & 1][tid] = xbv;
        q1_lds[s & 1][tid] = q1v;
        q2_lds[s & 1][tid] = q2v;
        __syncthreads();  // LDS visible + per-wave vmcnt(0) drain (stores at LLC)
        if (tid == 0) {
            __hip_atomic_store(flag_self, (unsigned)(s + 1), __ATOMIC_RELEASE, AGENT);
        }
    };

    // ---- step 0: xbar = x, q = 0, plain loads from input ----
    step_math(x[g_xp], x[g_xm],
              x[b * PLANE + l_yp], x[b * PLANE + l_ym],
              x[b * PLANE + l_tp], x[b * PLANE + l_tm],
              0.f, 0.f, 0.f);
    publish(0);

    for (int s = 1; s < TSTEPS; ++s) {
        const int r1 = (s - 1) & 1;
        const size_t r3 = (size_t)((s - 1) & (DEPTH - 1)) * NSITES;
        const unsigned need = (unsigned)s;

        // wait for both x-neighbor blocks to have published step s-1
        while (__hip_atomic_load(flag_xp, __ATOMIC_RELAXED, AGENT) < need ||
               __hip_atomic_load(flag_xm, __ATOMIC_RELAXED, AGENT) < need) {
        }

        union { float f[2]; unsigned long long u; } pkp, pkm;
        pkp.u = __hip_atomic_load(&pk_g[r3 + g_xp], __ATOMIC_RELAXED, AGENT);
        pkm.u = __hip_atomic_load(&pk_g[r3 + g_xm], __ATOMIC_RELAXED, AGENT);

        const float xbyp = xb_lds[r1][l_yp];
        const float xbym = xb_lds[r1][l_ym];
        const float xbtp = xb_lds[r1][l_tp];
        const float xbtm = xb_lds[r1][l_tm];
        const float q1ym = q1_lds[r1][l_ym];
        const float q2tm = q2_lds[r1][l_tm];

        step_math(pkp.f[0], pkm.f[0], xbyp, xbym, xbtp, xbtm,
                  pkm.f[1], q1ym, q2tm);

        if (s < TSTEPS - 1) publish(s);
    }

    out[idx] = x0v;   // x1 after step 127
}

extern "C" void kernel_launch(void* const* d_in, const int* in_sizes, int n_in,
                              void* d_out, int out_size, void* d_ws, size_t ws_size,
                              hipStream_t stream) {
    const float* x   = (const float*)d_in[0];
    const float* lam = (const float*)d_in[1];
    const float* tau = (const float*)d_in[2];
    const float* sig = (const float*)d_in[3];
    const float* th  = (const float*)d_in[4];
    float* out = (float*)d_out;

    // ws layout: DEPTH*NSITES packed u64 (8 MB), then flags (256 * 128B = 32 KB)
    unsigned long long* pk_g = (unsigned long long*)d_ws;
    unsigned* flags = (unsigned*)(pk_g + (size_t)DEPTH * NSITES);

    // ws is poisoned to 0xAA before every timed call: zero the flag block
    hipMemsetAsync(flags, 0, NBLK * 32 * sizeof(unsigned), stream);

    void* args[] = {
        (void*)&x, (void*)&lam, (void*)&tau, (void*)&sig, (void*)&th,
        (void*)&pk_g, (void*)&flags, (void*)&out
    };
    hipLaunchCooperativeKernel((const void*)pdhg_persist,
                               dim3(NBLK), dim3(PLANE), args, 0, stream);
}